// Round 8
// baseline (102.092 us; speedup 1.0000x reference)
//
#include <hip/hip_runtime.h>
#include <math.h>

#define NEL   4096
#define NT    1024           // pav block: 16 waves
#define HALF  512            // threads per array half (sorted-range ownership)
#define EPT   8              // sorted elements per half-thread
#define CPT   4              // original indices per thread (both arrays)
#define LPI   4              // lanes cooperating per i in count kernel
#define QPAD  1032           // 1024 + 8 words: quarter q offset by 8 banks

// bank-conflict-breaking padded index (one pad slot every 8 elements)
#define IX(p) ((p) + ((p) >> 3))

// wave-synchronous LDS fence (lanes lockstep; drains own wave's ds ops)
#define WSYNC() asm volatile("s_waitcnt lgkmcnt(0)" ::: "memory")

// ---------------------------------------------------------------------------
// Kernel A: owner-computed stable descending ranks; no memset, no atomics.
// grid (64, 2) x 256 threads. Each i owned by 4 lanes (quarter-j each);
// rank combined via shfl_xor butterfly. Owner lanes write BOTH
// counts[i] = r  and  sortedv[r] = x[i]  (enables scatter-free consumer).
// ---------------------------------------------------------------------------
__global__ __launch_bounds__(256)
void count_kernel(const float* __restrict__ pred,
                  const float* __restrict__ target,
                  unsigned int* __restrict__ counts,
                  float* __restrict__ sortedv) {
  __shared__ float jv[4 * QPAD];       // 4 quarters, +8-word stagger
  const int arr = blockIdx.y;
  const float* __restrict__ x = arr ? target : pred;
  const int tid = threadIdx.x;
  const int q   = tid & (LPI - 1);           // j-quarter 0..3
  const int i   = blockIdx.x * 64 + (tid >> 2);

  // stage all 4096 values into staggered quarters (coalesced float4)
  {
    const float4* x4 = (const float4*)x;
    for (int w4 = tid; w4 < NEL / 4; w4 += 256) {
      const int qq = w4 >> 8;                // 256 float4 per quarter
      ((float4*)(jv + qq * QPAD))[w4 & 255] = x4[w4];
    }
  }
  __syncthreads();

  const float xi = jv[(i >> 10) * QPAD + (i & 1023)];
  const float4* mv = (const float4*)(jv + q * QPAD);
  unsigned int c = 0;
#pragma unroll 8
  for (int t4 = 0; t4 < 256; t4++) {
    const float4 v = mv[t4];
    const int j = q * 1024 + 4 * t4;
    c += (v.x > xi || (v.x == xi && j + 0 < i)) ? 1u : 0u;
    c += (v.y > xi || (v.y == xi && j + 1 < i)) ? 1u : 0u;
    c += (v.z > xi || (v.z == xi && j + 2 < i)) ? 1u : 0u;
    c += (v.w > xi || (v.w == xi && j + 3 < i)) ? 1u : 0u;
  }
  // butterfly across the 4 cooperating lanes -> all hold the full rank
  c += __shfl_xor((int)c, 1);
  c += __shfl_xor((int)c, 2);
  if (q == 0) counts[arr * NEL + i] = c;       // sorted position of i
  if (q == 1) sortedv[arr * NEL + c] = xi;     // value in sorted order
}

// ---------------------------------------------------------------------------
// division-free single-boundary pool merge of [lo,mid) and [mid,hi).
// invariant: block [a,b] has C[a] == C[b] == b-a+1. P accessed via IX().
// ---------------------------------------------------------------------------
__device__ inline void pav_merge(double* P, int* C, const int lo, const int mid,
                                 const int hi) {
  const int llen = C[mid - 1];
  int cs = mid - llen;
  const int rlen = C[mid];
  int ce = mid + rlen - 1;
  const double Pmid = P[IX(mid)];
  double Pcs = P[IX(cs)], Pce1 = P[IX(ce + 1)];
  if ((Pmid - Pcs) * (double)rlen <= (Pce1 - Pmid) * (double)llen) {
    bool changed = true;
    while (changed) {
      changed = false;
      while (cs > lo) {                  // absorb left block if mean <= mu
        const int l2 = C[cs - 1];
        const double Pl = P[IX(cs - l2)];
        if ((Pcs - Pl) * (double)(ce - cs + 1) <= (Pce1 - Pcs) * (double)l2) {
          cs -= l2; Pcs = Pl; changed = true;
        } else break;
      }
      while (ce < hi - 1) {              // absorb right block if mean >= mu
        const int l2 = C[ce + 1];
        const double Pr = P[IX(ce + 1 + l2)];
        if ((Pr - Pce1) * (double)(ce - cs + 1) >= (Pce1 - Pcs) * (double)l2) {
          ce += l2; Pce1 = Pr; changed = true;
        } else break;
      }
    }
    const int len = ce - cs + 1;
    C[cs] = len;
    C[ce] = len;
  }
}

// ---------------------------------------------------------------------------
// Kernel B (one block, 1024 threads): coalesced loads of counts+sortedv ->
// register prefix -> register-minimax local PAV -> wave-sync merges ->
// cross-wave merges -> ranks (registers) -> loss. 5 barriers.
// ---------------------------------------------------------------------------
__global__ __launch_bounds__(NT)
void pav_loss_kernel(const unsigned int* __restrict__ counts,
                     const float* __restrict__ sortedv,
                     float* __restrict__ loss_out) {
  __shared__ float  s_rank[2][IX(NEL - 1) + 1];  // padded sorted-order ranks
  __shared__ double s_P[2][IX(NEL) + 1];         // padded prefix sums of z
  __shared__ int    s_cnt[2][NEL];               // block stamps -> bstart
  __shared__ double s_wsum[2][HALF / 64];
  __shared__ int    s_nb[2];
  __shared__ double s_red[NT / 64][5];

  const int tid  = threadIdx.x;
  const int lane = tid & 63;
  const int wid  = tid >> 6;

  // ---- correlation gather indices (orig idx 4tid..4tid+3, both arrays) ---
  int rp[CPT], rt[CPT];
  {
    const uint4 a = ((const uint4*)counts)[tid];
    const uint4 b = ((const uint4*)counts)[NEL / 4 + tid];
    rp[0] = (int)a.x; rp[1] = (int)a.y; rp[2] = (int)a.z; rp[3] = (int)a.w;
    rt[0] = (int)b.x; rt[1] = (int)b.y; rt[2] = (int)b.z; rt[3] = (int)b.w;
  }

  // ---- sorted-range ownership: own 8 sorted values, coalesced ------------
  const int arr = tid >> 9;            // 0: pred, 1: target
  const int tA  = tid & (HALF - 1);
  const int wA  = tA >> 6;             // wave within half, 0..7
  const int b0  = tA * EPT;
  double* P = s_P[arr];
  int*    C = s_cnt[arr];

  float xv[EPT];
  {
    const float4 v0 = ((const float4*)sortedv)[arr * (NEL / 4) + 2 * tA];
    const float4 v1 = ((const float4*)sortedv)[arr * (NEL / 4) + 2 * tA + 1];
    xv[0] = v0.x; xv[1] = v0.y; xv[2] = v0.z; xv[3] = v0.w;
    xv[4] = v1.x; xv[5] = v1.y; xv[6] = v1.z; xv[7] = v1.w;
  }

  // ---- register prefix of z_p = s_p - (NEL - p) over own 8 elements ------
  double c[EPT];
  {
    double acc = 0.0;
#pragma unroll
    for (int e = 0; e < EPT; e++) {
      acc += (double)xv[e] - (double)(NEL - (b0 + e));
      c[e] = acc;
    }
  }
  const double tot = c[EPT - 1];
  double sc = tot;                     // wave-inclusive scan of thread totals
#pragma unroll
  for (int d = 1; d < 64; d <<= 1) {
    const double o = __shfl_up(sc, d, 64);
    if (lane >= d) sc += o;
  }
  if (lane == 63) s_wsum[arr][wA] = sc;
  __syncthreads();                                   // B1
  double wexcl = 0.0;
#pragma unroll
  for (int w = 0; w < HALF / 64; w++)
    wexcl += (w < wA) ? s_wsum[arr][w] : 0.0;
  const double excl = wexcl + (sc - tot);            // == P[b0]
#pragma unroll
  for (int e = 0; e < EPT; e++) P[IX(b0 + 1 + e)] = excl + c[e];
  if (lane == 0) P[IX(b0)] = excl;     // wave-span base (benign 1-ulp race
                                       //  with prev lane63; proven R4/R6/R7)

  // ---- local PAV on own 8 elements: register minimax, division-free ------
  double nmx[EPT]; int dmx[EPT];
  double vn[EPT];  int vd[EPT];
  {
#pragma unroll
    for (int j = 0; j < EPT; j++) {
      nmx[j] = c[7] - (j ? c[j - 1] : 0.0);
      dmx[j] = EPT - j;
    }
    double mn = nmx[0]; int md = dmx[0];
#pragma unroll
    for (int j = 1; j < EPT; j++)
      if (nmx[j] * (double)md < mn * (double)dmx[j]) { mn = nmx[j]; md = dmx[j]; }
    vn[7] = mn; vd[7] = md;
#pragma unroll
    for (int p = EPT - 2; p >= 0; p--) {
#pragma unroll
      for (int j = 0; j < EPT - 1; j++) {
        if (j <= p) {
          const double cnum = c[p] - (j ? c[j - 1] : 0.0);
          const int cden = p - j + 1;
          if (cnum * (double)dmx[j] > nmx[j] * (double)cden) {
            nmx[j] = cnum; dmx[j] = cden;
          }
        }
      }
      double mn2 = nmx[0]; int md2 = dmx[0];
#pragma unroll
      for (int j = 1; j < EPT - 1; j++) {
        if (j <= p) {
          if (nmx[j] * (double)md2 < mn2 * (double)dmx[j]) {
            mn2 = nmx[j]; md2 = dmx[j];
          }
        }
      }
      vn[p] = mn2; vd[p] = md2;
    }
  }
  // stamps: runs of identical (vn,vd) pairs = local PAV blocks
  {
    int runstart = b0;
#pragma unroll
    for (int e = 1; e < EPT; e++) {
      const bool neq = (vd[e] != vd[e - 1]) ||
                       (__double_as_longlong(vn[e]) !=
                        __double_as_longlong(vn[e - 1]));
      if (neq) {
        const int len = b0 + e - runstart;
        C[runstart] = len;
        C[b0 + e - 1] = len;
        runstart = b0 + e;
      }
    }
    const int len = b0 + EPT - runstart;
    C[runstart] = len;
    C[b0 + EPT - 1] = len;
  }
  WSYNC();   // own wave's P + stamps visible wave-wide (lockstep)

  // ---- within-wave levels m = 8..256 (wave span 512), wave-synchronous ---
  const int wbase = wA * 512;
#pragma unroll
  for (int m = EPT; m <= 256; m <<= 1) {
    const int nm = 512 / (2 * m);
    if (lane < nm) {
      const int lo = wbase + lane * 2 * m;
      pav_merge(P, C, lo, lo + m, lo + 2 * m);
    }
    WSYNC();
  }
  __syncthreads();                                   // B2

  // ---- cross-wave levels m = 512..2048 + walk: wave 0 of each half -------
  if (wA == 0) {
#pragma unroll
    for (int m = 512; m <= 2048; m <<= 1) {
      const int nm = NEL / (2 * m);
      if (lane < nm) {
        const int lo = lane * 2 * m;
        pav_merge(P, C, lo, lo + m, lo + 2 * m);
      }
      WSYNC();
    }
    if (lane == 0) {                   // walk block list -> bstart (aliased;
      int s = 0, b = 0;                //  reads lead writes)
      while (s < NEL) {
        const int cc = C[s];
        C[b] = s;
        b++;
        s += cc;
      }
      s_nb[arr] = b;
    }
  }
  __syncthreads();                                   // B3

  // ---- rank at own sorted positions (values already in registers) --------
  const int nb = s_nb[arr];
#pragma unroll
  for (int e = 0; e < EPT; e++) {
    const int p = b0 + e;
    int lo = 0, hi = nb - 1;
    while (lo < hi) {
      const int md = (lo + hi + 1) >> 1;
      if (C[md] <= p) lo = md; else hi = md - 1;
    }
    const int st = C[lo];
    const int en = (lo + 1 < nb) ? C[lo + 1] : NEL;
    const double v = (P[IX(en)] - P[IX(st)]) / (double)(en - st);
    s_rank[arr][IX(p)] = (float)((double)xv[e] - v);
  }
  __syncthreads();                                   // B4

  // ---- Pearson loss: gather both rank vectors via rp/rt ------------------
  double Sp = 0.0, Sq = 0.0, Spp = 0.0, Sqq = 0.0, Spq = 0.0;
#pragma unroll
  for (int e = 0; e < CPT; e++) {
    const double p = (double)s_rank[0][IX(rp[e])];
    const double q = (double)s_rank[1][IX(rt[e])];
    Sp += p; Sq += q; Spp += p * p; Sqq += q * q; Spq += p * q;
  }
#pragma unroll
  for (int d = 32; d > 0; d >>= 1) {
    Sp  += __shfl_down(Sp,  d, 64);
    Sq  += __shfl_down(Sq,  d, 64);
    Spp += __shfl_down(Spp, d, 64);
    Sqq += __shfl_down(Sqq, d, 64);
    Spq += __shfl_down(Spq, d, 64);
  }
  if (lane == 0) {
    s_red[wid][0] = Sp;  s_red[wid][1] = Sq;  s_red[wid][2] = Spp;
    s_red[wid][3] = Sqq; s_red[wid][4] = Spq;
  }
  __syncthreads();                                   // B5
  if (tid == 0) {
    double a0 = 0, a1 = 0, a2 = 0, a3 = 0, a4 = 0;
    for (int w = 0; w < NT / 64; w++) {
      a0 += s_red[w][0]; a1 += s_red[w][1]; a2 += s_red[w][2];
      a3 += s_red[w][3]; a4 += s_red[w][4];
    }
    const double n  = (double)NEL;
    const double mp = a0 / n, mq = a1 / n;
    const double cov = a4 - n * mp * mq;
    const double vp  = a2 - n * mp * mp;
    const double vq  = a3 - n * mq * mq;
    loss_out[0] = (float)(1.0 - cov / sqrt(vp * vq));
  }
}

// ---------------------------------------------------------------------------
extern "C" void kernel_launch(void* const* d_in, const int* in_sizes, int n_in,
                              void* d_out, int out_size, void* d_ws, size_t ws_size,
                              hipStream_t stream) {
  const float* pred   = (const float*)d_in[0];
  const float* target = (const float*)d_in[1];
  unsigned int* counts  = (unsigned int*)d_ws;            // 2*NEL u32 = 32 KB
  float*        sortedv = (float*)((char*)d_ws + 2 * NEL * sizeof(unsigned int));
  float* out = (float*)d_out;

  hipLaunchKernelGGL(count_kernel, dim3(64, 2), dim3(256), 0, stream,
                     pred, target, counts, sortedv);
  hipLaunchKernelGGL(pav_loss_kernel, dim3(1), dim3(NT), 0, stream,
                     counts, sortedv, out);
}

// Round 9
// 100.111 us; speedup vs baseline: 1.0198x; 1.0198x over previous
//
#include <hip/hip_runtime.h>
#include <math.h>

#define NEL   4096
#define NT    1024           // pav block: 16 waves
#define HALF  512            // threads per array half (sorted-range ownership)
#define EPT   8              // sorted elements per half-thread
#define CPT   4              // original indices per thread (both arrays)
#define LPI   4              // lanes cooperating per i in count kernel
#define QPAD  1032           // 1024 + 8 words: quarter q offset by 8 banks

// bank-conflict-breaking padded index (one pad slot every 8 elements)
#define IX(p) ((p) + ((p) >> 3))

// wave-synchronous LDS fence (lanes lockstep; drains own wave's ds ops)
#define WSYNC() asm volatile("s_waitcnt lgkmcnt(0)" ::: "memory")

// ---------------------------------------------------------------------------
// Kernel A: owner-computed stable descending ranks. No memset, no atomics,
// no scattered global writes. grid (64, 2) x 256 threads; 4 lanes per i
// (quarter-j each), combined via shfl_xor. counts lines are written
// coalesced by exactly ONE block each (clean single-writer line ownership —
// the R8 post-mortem rule; the scattered sortedv write is gone).
// ---------------------------------------------------------------------------
__global__ __launch_bounds__(256)
void count_kernel(const float* __restrict__ pred,
                  const float* __restrict__ target,
                  unsigned int* __restrict__ counts) {
  __shared__ float jv[4 * QPAD];       // 4 quarters, +8-word stagger
  const int arr = blockIdx.y;
  const float* __restrict__ x = arr ? target : pred;
  const int tid = threadIdx.x;
  const int q   = tid & (LPI - 1);           // j-quarter 0..3
  const int i   = blockIdx.x * 64 + (tid >> 2);

  // stage all 4096 values into staggered quarters (coalesced float4)
  {
    const float4* x4 = (const float4*)x;
    for (int w4 = tid; w4 < NEL / 4; w4 += 256) {
      const int qq = w4 >> 8;                // 256 float4 per quarter
      ((float4*)(jv + qq * QPAD))[w4 & 255] = x4[w4];
    }
  }
  __syncthreads();

  const float xi = jv[(i >> 10) * QPAD + (i & 1023)];
  const float4* mv = (const float4*)(jv + q * QPAD);
  unsigned int c = 0;
#pragma unroll 8
  for (int t4 = 0; t4 < 256; t4++) {
    const float4 v = mv[t4];
    const int j = q * 1024 + 4 * t4;
    c += (v.x > xi || (v.x == xi && j + 0 < i)) ? 1u : 0u;
    c += (v.y > xi || (v.y == xi && j + 1 < i)) ? 1u : 0u;
    c += (v.z > xi || (v.z == xi && j + 2 < i)) ? 1u : 0u;
    c += (v.w > xi || (v.w == xi && j + 3 < i)) ? 1u : 0u;
  }
  // butterfly across the 4 cooperating lanes -> all hold the full rank
  c += __shfl_xor((int)c, 1);
  c += __shfl_xor((int)c, 2);
  if (q == 0) counts[arr * NEL + i] = c;   // one 256 B span per wave
}

// ---------------------------------------------------------------------------
// division-free single-boundary pool merge of [lo,mid) and [mid,hi).
// invariant: block [a,b] has C[a] == C[b] == b-a+1. P accessed via IX().
// ---------------------------------------------------------------------------
__device__ inline void pav_merge(double* P, int* C, const int lo, const int mid,
                                 const int hi) {
  const int llen = C[mid - 1];
  int cs = mid - llen;
  const int rlen = C[mid];
  int ce = mid + rlen - 1;
  const double Pmid = P[IX(mid)];
  double Pcs = P[IX(cs)], Pce1 = P[IX(ce + 1)];
  if ((Pmid - Pcs) * (double)rlen <= (Pce1 - Pmid) * (double)llen) {
    bool changed = true;
    while (changed) {
      changed = false;
      while (cs > lo) {                  // absorb left block if mean <= mu
        const int l2 = C[cs - 1];
        const double Pl = P[IX(cs - l2)];
        if ((Pcs - Pl) * (double)(ce - cs + 1) <= (Pce1 - Pcs) * (double)l2) {
          cs -= l2; Pcs = Pl; changed = true;
        } else break;
      }
      while (ce < hi - 1) {              // absorb right block if mean >= mu
        const int l2 = C[ce + 1];
        const double Pr = P[IX(ce + 1 + l2)];
        if ((Pr - Pce1) * (double)(ce - cs + 1) >= (Pce1 - Pcs) * (double)l2) {
          ce += l2; Pce1 = Pr; changed = true;
        } else break;
      }
    }
    const int len = ce - cs + 1;
    C[cs] = len;
    C[ce] = len;
  }
}

// ---------------------------------------------------------------------------
// Kernel B — byte-identical to R7's proven pav_loss_kernel (reads pristine
// pred/target + counts; padded-LDS scatter; register-minimax local PAV).
// ---------------------------------------------------------------------------
__global__ __launch_bounds__(NT)
void pav_loss_kernel(const float* __restrict__ pred,
                     const float* __restrict__ target,
                     const unsigned int* __restrict__ counts,
                     float* __restrict__ loss_out) {
  __shared__ float  s_val[2][IX(NEL - 1) + 2];   // padded; values then ranks
  __shared__ double s_P[2][IX(NEL) + 1];         // padded prefix sums of z
  __shared__ int    s_cnt[2][NEL];               // block stamps -> bstart
  __shared__ double s_wsum[2][HALF / 64];
  __shared__ int    s_nb[2];
  __shared__ double s_red[NT / 64][5];

  const int tid  = threadIdx.x;
  const int lane = tid & 63;
  const int wid  = tid >> 6;

  // ---- phase A: read counts (= sorted positions) + values, scatter -------
  int rp[CPT], rt[CPT];
  {
    const uint4 a = ((const uint4*)counts)[tid];
    const uint4 b = ((const uint4*)counts)[NEL / 4 + tid];
    rp[0] = (int)a.x; rp[1] = (int)a.y; rp[2] = (int)a.z; rp[3] = (int)a.w;
    rt[0] = (int)b.x; rt[1] = (int)b.y; rt[2] = (int)b.z; rt[3] = (int)b.w;
    const float4 xp = ((const float4*)pred)[tid];
    const float4 xt = ((const float4*)target)[tid];
    s_val[0][IX(rp[0])] = xp.x; s_val[0][IX(rp[1])] = xp.y;
    s_val[0][IX(rp[2])] = xp.z; s_val[0][IX(rp[3])] = xp.w;
    s_val[1][IX(rt[0])] = xt.x; s_val[1][IX(rt[1])] = xt.y;
    s_val[1][IX(rt[2])] = xt.z; s_val[1][IX(rt[3])] = xt.w;
  }
  __syncthreads();                                   // B1

  // ---- sorted-range ownership --------------------------------------------
  const int arr = tid >> 9;            // 0: pred, 1: target
  const int tA  = tid & (HALF - 1);
  const int wA  = tA >> 6;             // wave within half, 0..7
  const int b0  = tA * EPT;
  double* P = s_P[arr];
  int*    C = s_cnt[arr];

  // ---- register prefix of z_p = s_p - (NEL - p) over own 8 elements ------
  double c[EPT];
  {
    double acc = 0.0;
#pragma unroll
    for (int e = 0; e < EPT; e++) {
      const int p = b0 + e;
      acc += (double)s_val[arr][IX(p)] - (double)(NEL - p);
      c[e] = acc;
    }
  }
  const double tot = c[EPT - 1];
  double sc = tot;                     // wave-inclusive scan of thread totals
#pragma unroll
  for (int d = 1; d < 64; d <<= 1) {
    const double o = __shfl_up(sc, d, 64);
    if (lane >= d) sc += o;
  }
  if (lane == 63) s_wsum[arr][wA] = sc;
  __syncthreads();                                   // B2
  double wexcl = 0.0;
#pragma unroll
  for (int w = 0; w < HALF / 64; w++)
    wexcl += (w < wA) ? s_wsum[arr][w] : 0.0;
  const double excl = wexcl + (sc - tot);            // == P[b0]
#pragma unroll
  for (int e = 0; e < EPT; e++) P[IX(b0 + 1 + e)] = excl + c[e];
  if (lane == 0) P[IX(b0)] = excl;     // bit-identical to neighbor's write

  // ---- local PAV on own 8 elements: register minimax, division-free ------
  double nmx[EPT]; int dmx[EPT];
  double vn[EPT];  int vd[EPT];
  {
#pragma unroll
    for (int j = 0; j < EPT; j++) {
      nmx[j] = c[7] - (j ? c[j - 1] : 0.0);
      dmx[j] = EPT - j;
    }
    double mn = nmx[0]; int md = dmx[0];
#pragma unroll
    for (int j = 1; j < EPT; j++)
      if (nmx[j] * (double)md < mn * (double)dmx[j]) { mn = nmx[j]; md = dmx[j]; }
    vn[7] = mn; vd[7] = md;
#pragma unroll
    for (int p = EPT - 2; p >= 0; p--) {
#pragma unroll
      for (int j = 0; j < EPT - 1; j++) {
        if (j <= p) {
          const double cnum = c[p] - (j ? c[j - 1] : 0.0);
          const int cden = p - j + 1;
          if (cnum * (double)dmx[j] > nmx[j] * (double)cden) {
            nmx[j] = cnum; dmx[j] = cden;
          }
        }
      }
      double mn2 = nmx[0]; int md2 = dmx[0];
#pragma unroll
      for (int j = 1; j < EPT - 1; j++) {
        if (j <= p) {
          if (nmx[j] * (double)md2 < mn2 * (double)dmx[j]) {
            mn2 = nmx[j]; md2 = dmx[j];
          }
        }
      }
      vn[p] = mn2; vd[p] = md2;
    }
  }
  // stamps: runs of identical (vn,vd) pairs = local PAV blocks
  {
    int runstart = b0;
#pragma unroll
    for (int e = 1; e < EPT; e++) {
      const bool neq = (vd[e] != vd[e - 1]) ||
                       (__double_as_longlong(vn[e]) !=
                        __double_as_longlong(vn[e - 1]));
      if (neq) {
        const int len = b0 + e - runstart;
        C[runstart] = len;
        C[b0 + e - 1] = len;
        runstart = b0 + e;
      }
    }
    const int len = b0 + EPT - runstart;
    C[runstart] = len;
    C[b0 + EPT - 1] = len;
  }
  WSYNC();   // own wave's P + stamps visible wave-wide (lockstep)

  // ---- within-wave levels m = 8..256 (wave span 512), wave-synchronous ---
  const int wbase = wA * 512;
#pragma unroll
  for (int m = EPT; m <= 256; m <<= 1) {
    const int nm = 512 / (2 * m);
    if (lane < nm) {
      const int lo = wbase + lane * 2 * m;
      pav_merge(P, C, lo, lo + m, lo + 2 * m);
    }
    WSYNC();
  }
  __syncthreads();                                   // B3

  // ---- cross-wave levels m = 512..2048 + walk: wave 0 of each half -------
  if (wA == 0) {
#pragma unroll
    for (int m = 512; m <= 2048; m <<= 1) {
      const int nm = NEL / (2 * m);
      if (lane < nm) {
        const int lo = lane * 2 * m;
        pav_merge(P, C, lo, lo + m, lo + 2 * m);
      }
      WSYNC();
    }
    if (lane == 0) {                   // walk block list -> bstart (aliased;
      int s = 0, b = 0;                //  reads lead writes)
      while (s < NEL) {
        const int cc = C[s];
        C[b] = s;
        b++;
        s += cc;
      }
      s_nb[arr] = b;
    }
  }
  __syncthreads();                                   // B4

  // ---- rank at own sorted positions, in place ----------------------------
  const int nb = s_nb[arr];
#pragma unroll
  for (int e = 0; e < EPT; e++) {
    const int p = b0 + e;
    int lo = 0, hi = nb - 1;
    while (lo < hi) {
      const int md = (lo + hi + 1) >> 1;
      if (C[md] <= p) lo = md; else hi = md - 1;
    }
    const int st = C[lo];
    const int en = (lo + 1 < nb) ? C[lo + 1] : NEL;
    const double v = (P[IX(en)] - P[IX(st)]) / (double)(en - st);
    s_val[arr][IX(p)] = (float)((double)s_val[arr][IX(p)] - v);
  }
  __syncthreads();                                   // B5

  // ---- Pearson loss: gather both rank vectors via rp/rt ------------------
  double Sp = 0.0, Sq = 0.0, Spp = 0.0, Sqq = 0.0, Spq = 0.0;
#pragma unroll
  for (int e = 0; e < CPT; e++) {
    const double p = (double)s_val[0][IX(rp[e])];
    const double q = (double)s_val[1][IX(rt[e])];
    Sp += p; Sq += q; Spp += p * p; Sqq += q * q; Spq += p * q;
  }
#pragma unroll
  for (int d = 32; d > 0; d >>= 1) {
    Sp  += __shfl_down(Sp,  d, 64);
    Sq  += __shfl_down(Sq,  d, 64);
    Spp += __shfl_down(Spp, d, 64);
    Sqq += __shfl_down(Sqq, d, 64);
    Spq += __shfl_down(Spq, d, 64);
  }
  if (lane == 0) {
    s_red[wid][0] = Sp;  s_red[wid][1] = Sq;  s_red[wid][2] = Spp;
    s_red[wid][3] = Sqq; s_red[wid][4] = Spq;
  }
  __syncthreads();                                   // B6
  if (tid == 0) {
    double a0 = 0, a1 = 0, a2 = 0, a3 = 0, a4 = 0;
    for (int w = 0; w < NT / 64; w++) {
      a0 += s_red[w][0]; a1 += s_red[w][1]; a2 += s_red[w][2];
      a3 += s_red[w][3]; a4 += s_red[w][4];
    }
    const double n  = (double)NEL;
    const double mp = a0 / n, mq = a1 / n;
    const double cov = a4 - n * mp * mq;
    const double vp  = a2 - n * mp * mp;
    const double vq  = a3 - n * mq * mq;
    loss_out[0] = (float)(1.0 - cov / sqrt(vp * vq));
  }
}

// ---------------------------------------------------------------------------
extern "C" void kernel_launch(void* const* d_in, const int* in_sizes, int n_in,
                              void* d_out, int out_size, void* d_ws, size_t ws_size,
                              hipStream_t stream) {
  const float* pred   = (const float*)d_in[0];
  const float* target = (const float*)d_in[1];
  unsigned int* counts = (unsigned int*)d_ws;   // 2 * NEL u32 = 32 KB
  float* out = (float*)d_out;

  hipLaunchKernelGGL(count_kernel, dim3(64, 2), dim3(256), 0, stream,
                     pred, target, counts);
  hipLaunchKernelGGL(pav_loss_kernel, dim3(1), dim3(NT), 0, stream,
                     pred, target, counts, out);
}

// Round 10
// 98.332 us; speedup vs baseline: 1.0382x; 1.0181x over previous
//
#include <hip/hip_runtime.h>
#include <math.h>

#define NEL   4096
#define NT    1024           // pav block: 16 waves
#define HALF  512            // threads per array half (sorted-range ownership)
#define EPT   8              // sorted elements per half-thread
#define CPT   4              // original indices per thread (both arrays)
#define LPI   4              // lanes cooperating per i in count kernel
#define QPAD  1032           // 1024 + 8 words: quarter q offset by 8 banks

// bank-conflict-breaking padded index (one pad slot every 8 elements)
#define IX(p) ((p) + ((p) >> 3))

// wave-synchronous LDS fence (lanes lockstep; drains own wave's ds ops)
#define WSYNC() asm volatile("s_waitcnt lgkmcnt(0)" ::: "memory")

// ---------------------------------------------------------------------------
// Kernel A: owner-computed stable descending ranks. grid (64, 2) x 256.
// 4 lanes per i (quarter-j each), combined via shfl_xor; the owner lane
// publishes the rank with atomicExch — an atomic RMW at the device coherent
// point (fast consumer reads, per R2/R4/R7 vs R3/R8/R9 evidence) that needs
// NO zero-init, so the memset node is gone.
// ---------------------------------------------------------------------------
__global__ __launch_bounds__(256)
void count_kernel(const float* __restrict__ pred,
                  const float* __restrict__ target,
                  unsigned int* __restrict__ counts) {
  __shared__ float jv[4 * QPAD];       // 4 quarters, +8-word stagger
  const int arr = blockIdx.y;
  const float* __restrict__ x = arr ? target : pred;
  const int tid = threadIdx.x;
  const int q   = tid & (LPI - 1);           // j-quarter 0..3
  const int i   = blockIdx.x * 64 + (tid >> 2);

  // stage all 4096 values into staggered quarters (coalesced float4)
  {
    const float4* x4 = (const float4*)x;
    for (int w4 = tid; w4 < NEL / 4; w4 += 256) {
      const int qq = w4 >> 8;                // 256 float4 per quarter
      ((float4*)(jv + qq * QPAD))[w4 & 255] = x4[w4];
    }
  }
  __syncthreads();

  const float xi = jv[(i >> 10) * QPAD + (i & 1023)];
  const float4* mv = (const float4*)(jv + q * QPAD);
  unsigned int c = 0;
#pragma unroll 8
  for (int t4 = 0; t4 < 256; t4++) {
    const float4 v = mv[t4];
    const int j = q * 1024 + 4 * t4;
    c += (v.x > xi || (v.x == xi && j + 0 < i)) ? 1u : 0u;
    c += (v.y > xi || (v.y == xi && j + 1 < i)) ? 1u : 0u;
    c += (v.z > xi || (v.z == xi && j + 2 < i)) ? 1u : 0u;
    c += (v.w > xi || (v.w == xi && j + 3 < i)) ? 1u : 0u;
  }
  // butterfly across the 4 cooperating lanes -> all hold the full rank
  c += __shfl_xor((int)c, 1);
  c += __shfl_xor((int)c, 2);
  if (q == 0) atomicExch(&counts[arr * NEL + i], c);   // coherent-point write
}

// ---------------------------------------------------------------------------
// division-free single-boundary pool merge of [lo,mid) and [mid,hi).
// invariant: block [a,b] has C[a] == C[b] == b-a+1. P accessed via IX().
// ---------------------------------------------------------------------------
__device__ inline void pav_merge(double* P, int* C, const int lo, const int mid,
                                 const int hi) {
  const int llen = C[mid - 1];
  int cs = mid - llen;
  const int rlen = C[mid];
  int ce = mid + rlen - 1;
  const double Pmid = P[IX(mid)];
  double Pcs = P[IX(cs)], Pce1 = P[IX(ce + 1)];
  if ((Pmid - Pcs) * (double)rlen <= (Pce1 - Pmid) * (double)llen) {
    bool changed = true;
    while (changed) {
      changed = false;
      while (cs > lo) {                  // absorb left block if mean <= mu
        const int l2 = C[cs - 1];
        const double Pl = P[IX(cs - l2)];
        if ((Pcs - Pl) * (double)(ce - cs + 1) <= (Pce1 - Pcs) * (double)l2) {
          cs -= l2; Pcs = Pl; changed = true;
        } else break;
      }
      while (ce < hi - 1) {              // absorb right block if mean >= mu
        const int l2 = C[ce + 1];
        const double Pr = P[IX(ce + 1 + l2)];
        if ((Pr - Pce1) * (double)(ce - cs + 1) >= (Pce1 - Pcs) * (double)l2) {
          ce += l2; Pce1 = Pr; changed = true;
        } else break;
      }
    }
    const int len = ce - cs + 1;
    C[cs] = len;
    C[ce] = len;
  }
}

// ---------------------------------------------------------------------------
// Kernel B — byte-identical to R7's proven pav_loss_kernel.
// ---------------------------------------------------------------------------
__global__ __launch_bounds__(NT)
void pav_loss_kernel(const float* __restrict__ pred,
                     const float* __restrict__ target,
                     const unsigned int* __restrict__ counts,
                     float* __restrict__ loss_out) {
  __shared__ float  s_val[2][IX(NEL - 1) + 2];   // padded; values then ranks
  __shared__ double s_P[2][IX(NEL) + 1];         // padded prefix sums of z
  __shared__ int    s_cnt[2][NEL];               // block stamps -> bstart
  __shared__ double s_wsum[2][HALF / 64];
  __shared__ int    s_nb[2];
  __shared__ double s_red[NT / 64][5];

  const int tid  = threadIdx.x;
  const int lane = tid & 63;
  const int wid  = tid >> 6;

  // ---- phase A: read counts (= sorted positions) + values, scatter -------
  int rp[CPT], rt[CPT];
  {
    const uint4 a = ((const uint4*)counts)[tid];
    const uint4 b = ((const uint4*)counts)[NEL / 4 + tid];
    rp[0] = (int)a.x; rp[1] = (int)a.y; rp[2] = (int)a.z; rp[3] = (int)a.w;
    rt[0] = (int)b.x; rt[1] = (int)b.y; rt[2] = (int)b.z; rt[3] = (int)b.w;
    const float4 xp = ((const float4*)pred)[tid];
    const float4 xt = ((const float4*)target)[tid];
    s_val[0][IX(rp[0])] = xp.x; s_val[0][IX(rp[1])] = xp.y;
    s_val[0][IX(rp[2])] = xp.z; s_val[0][IX(rp[3])] = xp.w;
    s_val[1][IX(rt[0])] = xt.x; s_val[1][IX(rt[1])] = xt.y;
    s_val[1][IX(rt[2])] = xt.z; s_val[1][IX(rt[3])] = xt.w;
  }
  __syncthreads();                                   // B1

  // ---- sorted-range ownership --------------------------------------------
  const int arr = tid >> 9;            // 0: pred, 1: target
  const int tA  = tid & (HALF - 1);
  const int wA  = tA >> 6;             // wave within half, 0..7
  const int b0  = tA * EPT;
  double* P = s_P[arr];
  int*    C = s_cnt[arr];

  // ---- register prefix of z_p = s_p - (NEL - p) over own 8 elements ------
  double c[EPT];
  {
    double acc = 0.0;
#pragma unroll
    for (int e = 0; e < EPT; e++) {
      const int p = b0 + e;
      acc += (double)s_val[arr][IX(p)] - (double)(NEL - p);
      c[e] = acc;
    }
  }
  const double tot = c[EPT - 1];
  double sc = tot;                     // wave-inclusive scan of thread totals
#pragma unroll
  for (int d = 1; d < 64; d <<= 1) {
    const double o = __shfl_up(sc, d, 64);
    if (lane >= d) sc += o;
  }
  if (lane == 63) s_wsum[arr][wA] = sc;
  __syncthreads();                                   // B2
  double wexcl = 0.0;
#pragma unroll
  for (int w = 0; w < HALF / 64; w++)
    wexcl += (w < wA) ? s_wsum[arr][w] : 0.0;
  const double excl = wexcl + (sc - tot);            // == P[b0]
#pragma unroll
  for (int e = 0; e < EPT; e++) P[IX(b0 + 1 + e)] = excl + c[e];
  if (lane == 0) P[IX(b0)] = excl;     // bit-identical to neighbor's write

  // ---- local PAV on own 8 elements: register minimax, division-free ------
  double nmx[EPT]; int dmx[EPT];
  double vn[EPT];  int vd[EPT];
  {
#pragma unroll
    for (int j = 0; j < EPT; j++) {
      nmx[j] = c[7] - (j ? c[j - 1] : 0.0);
      dmx[j] = EPT - j;
    }
    double mn = nmx[0]; int md = dmx[0];
#pragma unroll
    for (int j = 1; j < EPT; j++)
      if (nmx[j] * (double)md < mn * (double)dmx[j]) { mn = nmx[j]; md = dmx[j]; }
    vn[7] = mn; vd[7] = md;
#pragma unroll
    for (int p = EPT - 2; p >= 0; p--) {
#pragma unroll
      for (int j = 0; j < EPT - 1; j++) {
        if (j <= p) {
          const double cnum = c[p] - (j ? c[j - 1] : 0.0);
          const int cden = p - j + 1;
          if (cnum * (double)dmx[j] > nmx[j] * (double)cden) {
            nmx[j] = cnum; dmx[j] = cden;
          }
        }
      }
      double mn2 = nmx[0]; int md2 = dmx[0];
#pragma unroll
      for (int j = 1; j < EPT - 1; j++) {
        if (j <= p) {
          if (nmx[j] * (double)md2 < mn2 * (double)dmx[j]) {
            mn2 = nmx[j]; md2 = dmx[j];
          }
        }
      }
      vn[p] = mn2; vd[p] = md2;
    }
  }
  // stamps: runs of identical (vn,vd) pairs = local PAV blocks
  {
    int runstart = b0;
#pragma unroll
    for (int e = 1; e < EPT; e++) {
      const bool neq = (vd[e] != vd[e - 1]) ||
                       (__double_as_longlong(vn[e]) !=
                        __double_as_longlong(vn[e - 1]));
      if (neq) {
        const int len = b0 + e - runstart;
        C[runstart] = len;
        C[b0 + e - 1] = len;
        runstart = b0 + e;
      }
    }
    const int len = b0 + EPT - runstart;
    C[runstart] = len;
    C[b0 + EPT - 1] = len;
  }
  WSYNC();   // own wave's P + stamps visible wave-wide (lockstep)

  // ---- within-wave levels m = 8..256 (wave span 512), wave-synchronous ---
  const int wbase = wA * 512;
#pragma unroll
  for (int m = EPT; m <= 256; m <<= 1) {
    const int nm = 512 / (2 * m);
    if (lane < nm) {
      const int lo = wbase + lane * 2 * m;
      pav_merge(P, C, lo, lo + m, lo + 2 * m);
    }
    WSYNC();
  }
  __syncthreads();                                   // B3

  // ---- cross-wave levels m = 512..2048 + walk: wave 0 of each half -------
  if (wA == 0) {
#pragma unroll
    for (int m = 512; m <= 2048; m <<= 1) {
      const int nm = NEL / (2 * m);
      if (lane < nm) {
        const int lo = lane * 2 * m;
        pav_merge(P, C, lo, lo + m, lo + 2 * m);
      }
      WSYNC();
    }
    if (lane == 0) {                   // walk block list -> bstart (aliased;
      int s = 0, b = 0;                //  reads lead writes)
      while (s < NEL) {
        const int cc = C[s];
        C[b] = s;
        b++;
        s += cc;
      }
      s_nb[arr] = b;
    }
  }
  __syncthreads();                                   // B4

  // ---- rank at own sorted positions, in place ----------------------------
  const int nb = s_nb[arr];
#pragma unroll
  for (int e = 0; e < EPT; e++) {
    const int p = b0 + e;
    int lo = 0, hi = nb - 1;
    while (lo < hi) {
      const int md = (lo + hi + 1) >> 1;
      if (C[md] <= p) lo = md; else hi = md - 1;
    }
    const int st = C[lo];
    const int en = (lo + 1 < nb) ? C[lo + 1] : NEL;
    const double v = (P[IX(en)] - P[IX(st)]) / (double)(en - st);
    s_val[arr][IX(p)] = (float)((double)s_val[arr][IX(p)] - v);
  }
  __syncthreads();                                   // B5

  // ---- Pearson loss: gather both rank vectors via rp/rt ------------------
  double Sp = 0.0, Sq = 0.0, Spp = 0.0, Sqq = 0.0, Spq = 0.0;
#pragma unroll
  for (int e = 0; e < CPT; e++) {
    const double p = (double)s_val[0][IX(rp[e])];
    const double q = (double)s_val[1][IX(rt[e])];
    Sp += p; Sq += q; Spp += p * p; Sqq += q * q; Spq += p * q;
  }
#pragma unroll
  for (int d = 32; d > 0; d >>= 1) {
    Sp  += __shfl_down(Sp,  d, 64);
    Sq  += __shfl_down(Sq,  d, 64);
    Spp += __shfl_down(Spp, d, 64);
    Sqq += __shfl_down(Sqq, d, 64);
    Spq += __shfl_down(Spq, d, 64);
  }
  if (lane == 0) {
    s_red[wid][0] = Sp;  s_red[wid][1] = Sq;  s_red[wid][2] = Spp;
    s_red[wid][3] = Sqq; s_red[wid][4] = Spq;
  }
  __syncthreads();                                   // B6
  if (tid == 0) {
    double a0 = 0, a1 = 0, a2 = 0, a3 = 0, a4 = 0;
    for (int w = 0; w < NT / 64; w++) {
      a0 += s_red[w][0]; a1 += s_red[w][1]; a2 += s_red[w][2];
      a3 += s_red[w][3]; a4 += s_red[w][4];
    }
    const double n  = (double)NEL;
    const double mp = a0 / n, mq = a1 / n;
    const double cov = a4 - n * mp * mq;
    const double vp  = a2 - n * mp * mp;
    const double vq  = a3 - n * mq * mq;
    loss_out[0] = (float)(1.0 - cov / sqrt(vp * vq));
  }
}

// ---------------------------------------------------------------------------
extern "C" void kernel_launch(void* const* d_in, const int* in_sizes, int n_in,
                              void* d_out, int out_size, void* d_ws, size_t ws_size,
                              hipStream_t stream) {
  const float* pred   = (const float*)d_in[0];
  const float* target = (const float*)d_in[1];
  unsigned int* counts = (unsigned int*)d_ws;   // 2 * NEL u32 = 32 KB
  float* out = (float*)d_out;

  hipLaunchKernelGGL(count_kernel, dim3(64, 2), dim3(256), 0, stream,
                     pred, target, counts);
  hipLaunchKernelGGL(pav_loss_kernel, dim3(1), dim3(NT), 0, stream,
                     pred, target, counts, out);
}